// Round 4
// baseline (375.145 us; speedup 1.0000x reference)
//
#include <hip/hip_runtime.h>
#include <math.h>

#define S_LEN 2048
#define D_DIM 1024
#define NB    4

typedef __bf16 bf16_t;
typedef __bf16 bf16x8 __attribute__((ext_vector_type(8)));
typedef float  f32x4  __attribute__((ext_vector_type(4)));

#define BM 128
#define BN 128
#define BK 64   // 64 bf16 = 128 B per row

// async global->LDS, 16B per lane; lds ptr must be wave-uniform base (HW adds lane*16)
__device__ __forceinline__ void async16(const void* g, void* l) {
    __builtin_amdgcn_global_load_lds(
        (__attribute__((address_space(1))) const void*)g,
        (__attribute__((address_space(3))) void*)l, 16, 0, 0);
}

// C[128x128] tile of A[M,K] * Bt[N,K]^T, bf16 in, fp32 acc.
// BK=64 2-barrier K-loop. LDS bank swizzle: row r's 16B k-block kb stored at
// slot kb ^ (r&7); each 16-lane ds_read_b128 phase covers all 8 bank groups 2x.
__device__ __forceinline__ void gemm_bt_core(
    const bf16_t* __restrict__ A, const bf16_t* __restrict__ Bt,
    int lda, int ldb, int m0, int n0, int kTiles, f32x4 (&acc)[4][4])
{
    __shared__ bf16_t lA[BM * BK];   // 16 KB
    __shared__ bf16_t lB[BN * BK];   // 16 KB
    const int t    = threadIdx.x;
    const int w    = t >> 6;               // wave 0..3
    const int lane = t & 63;
    const int wr   = w >> 1, wc = w & 1;   // 2x2 wave grid, each wave 64x64
    const int srow   = lane >> 3;                       // 0..7
    const int kb_src = ((lane & 7) ^ (lane >> 3)) * 8;  // bf16 offset in row
    const int fr = lane & 15, fq = lane >> 4;
    const int fof0 = (((0 * 4 + fq) ^ (fr & 7)) * 8);
    const int fof1 = (((1 * 4 + fq) ^ (fr & 7)) * 8);
    const bf16_t* paB0 = lA + (wr * 64 + fr) * BK + fof0;
    const bf16_t* paB1 = lA + (wr * 64 + fr) * BK + fof1;
    const bf16_t* pbB0 = lB + (wc * 64 + fr) * BK + fof0;
    const bf16_t* pbB1 = lB + (wc * 64 + fr) * BK + fof1;
    bf16_t* ldsA = lA + (w * 32) * BK;
    bf16_t* ldsB = lB + (w * 32) * BK;
    const bf16_t* gA = A  + (long)(m0 + w * 32 + srow) * lda + kb_src;
    const bf16_t* gB = Bt + (long)(n0 + w * 32 + srow) * ldb + kb_src;

#pragma unroll
    for (int mt = 0; mt < 4; ++mt)
#pragma unroll
        for (int nt = 0; nt < 4; ++nt)
            acc[mt][nt] = f32x4{0.f, 0.f, 0.f, 0.f};

    for (int kt = 0; kt < kTiles; ++kt) {
        const long k0 = (long)kt * BK;
#pragma unroll
        for (int i = 0; i < 4; ++i) {
            async16(gA + k0 + (long)(i * 8) * lda, ldsA + i * 8 * BK);
            async16(gB + k0 + (long)(i * 8) * ldb, ldsB + i * 8 * BK);
        }
        asm volatile("s_waitcnt vmcnt(0)" ::: "memory");
        __syncthreads();
#pragma unroll
        for (int h = 0; h < 2; ++h) {
            const bf16_t* pa = h ? paB1 : paB0;
            const bf16_t* pb = h ? pbB1 : pbB0;
            bf16x8 af[4], bfv[4];
#pragma unroll
            for (int mt = 0; mt < 4; ++mt)
                af[mt] = *(const bf16x8*)(pa + mt * 16 * BK);
#pragma unroll
            for (int nt = 0; nt < 4; ++nt)
                bfv[nt] = *(const bf16x8*)(pb + nt * 16 * BK);
#pragma unroll
            for (int mt = 0; mt < 4; ++mt)
#pragma unroll
                for (int nt = 0; nt < 4; ++nt)
                    acc[mt][nt] = __builtin_amdgcn_mfma_f32_16x16x32_bf16(
                        af[mt], bfv[nt], acc[mt][nt], 0, 0, 0);
        }
        __syncthreads();
    }
}

// W [K,N] fp32 -> Wt [N,K] bf16 (transpose+cast), 32x32 LDS tiles
__global__ __launch_bounds__(256) void k_tw(
    const float* __restrict__ Wq, const float* __restrict__ Wk,
    const float* __restrict__ Wv, bf16_t* __restrict__ Wt)
{
    __shared__ float tile[32][33];
    const int z = blockIdx.z;
    const float* W = (z == 0) ? Wq : ((z == 1) ? Wk : Wv);
    bf16_t* T = Wt + (long)z * D_DIM * D_DIM;
    const int tx = threadIdx.x, ty = threadIdx.y;
    const int x  = blockIdx.x * 32 + tx;   // n
    const int y0 = blockIdx.y * 32;        // k
#pragma unroll
    for (int j = ty; j < 32; j += 8) tile[j][tx] = W[(long)(y0 + j) * D_DIM + x];
    __syncthreads();
    const int x2 = blockIdx.y * 32 + tx;   // k
    const int y2 = blockIdx.x * 32;        // n
#pragma unroll
    for (int j = ty; j < 32; j += 8)
        T[(long)(y2 + j) * D_DIM + x2] = (bf16_t)tile[tx][j];
}

// WV [S,D] bf16 -> WVt [D,S] bf16 per batch
__global__ __launch_bounds__(256) void k_tv(
    const bf16_t* __restrict__ PrV, bf16_t* __restrict__ WVt)
{
    __shared__ bf16_t tile[32][33];
    const int b = blockIdx.z;
    const bf16_t* src = PrV + (long)b * S_LEN * D_DIM;
    bf16_t* dst = WVt + (long)b * D_DIM * S_LEN;
    const int tx = threadIdx.x, ty = threadIdx.y;
    const int x  = blockIdx.x * 32 + tx;   // d
    const int y0 = blockIdx.y * 32;        // s
#pragma unroll
    for (int j = ty; j < 32; j += 8) tile[j][tx] = src[(long)(y0 + j) * D_DIM + x];
    __syncthreads();
    const int x2 = blockIdx.y * 32 + tx;   // s
    const int y2 = blockIdx.x * 32;        // d
#pragma unroll
    for (int j = ty; j < 32; j += 8)
        dst[(long)(y2 + j) * S_LEN + x2] = tile[tx][j];
}

// Projections with FUSED fp32->bf16 A-staging: Pr_z = cast(X_z) @ Wt_z^T + bias_z.
// A-tile: fp32 global -> float4 loads -> cvt -> ds_write_b128 into swizzled LDS.
// B-tile (weights): global_load_lds as before. Deletes the separate f2b pass
// (saves 192 MB of round-trip traffic + one kernel's wall time).
__global__ __launch_bounds__(256) void k_gemm_proj(
    const float* __restrict__ q, const float* __restrict__ kk,
    const float* __restrict__ v, const bf16_t* __restrict__ Wt,
    const float* __restrict__ bq, const float* __restrict__ bk,
    const float* __restrict__ bv, bf16_t* __restrict__ Pr)
{
    __shared__ bf16_t lA[BM * BK];   // 16 KB
    __shared__ bf16_t lB[BN * BK];   // 16 KB
    const int z = blockIdx.z;
    const float* A32 = (z == 0) ? q : ((z == 1) ? kk : v);
    const bf16_t* Bt = Wt + (long)z * D_DIM * D_DIM;
    bf16_t* C        = Pr + (long)z * ((long)NB * S_LEN * D_DIM);
    const float* bias = (z == 0) ? bq : ((z == 1) ? bk : bv);
    const int m0 = blockIdx.x * BM, n0 = blockIdx.y * BN;

    const int t = threadIdx.x, w = t >> 6, lane = t & 63;
    const int wr = w >> 1, wc = w & 1;
    // B staging (async16, swizzled)
    const int srow   = lane >> 3;
    const int kb_src = ((lane & 7) ^ srow) * 8;
    bf16_t* ldsB = lB + (w * 32) * BK;
    const bf16_t* gB = Bt + (long)(n0 + w * 32 + srow) * D_DIM + kb_src;
    // A staging: 2 threads/row, each covers 32 fp32 (half the BK window)
    const int ar = t >> 1, ah = t & 1;
    const float* gA = A32 + (long)(m0 + ar) * D_DIM + ah * 32;
    bf16_t* wArow = lA + ar * BK;
    const int abase = ah * 4;         // first of 4 k-blocks this thread writes
    const int arm = ar & 7;
    // fragment read (same swizzled layout)
    const int fr = lane & 15, fq = lane >> 4;
    const int fof0 = ((fq ^ (fr & 7)) * 8);
    const int fof1 = (((4 + fq) ^ (fr & 7)) * 8);
    const bf16_t* paB0 = lA + (wr * 64 + fr) * BK + fof0;
    const bf16_t* paB1 = lA + (wr * 64 + fr) * BK + fof1;
    const bf16_t* pbB0 = lB + (wc * 64 + fr) * BK + fof0;
    const bf16_t* pbB1 = lB + (wc * 64 + fr) * BK + fof1;

    f32x4 acc[4][4];
#pragma unroll
    for (int mt = 0; mt < 4; ++mt)
#pragma unroll
        for (int nt = 0; nt < 4; ++nt)
            acc[mt][nt] = f32x4{0.f, 0.f, 0.f, 0.f};

    for (int kt = 0; kt < D_DIM / BK; ++kt) {
        // B: async global->LDS first so it overlaps A's load+cvt+write
#pragma unroll
        for (int i = 0; i < 4; ++i)
            async16(gB + (long)kt * BK + (long)(i * 8) * D_DIM, ldsB + i * 8 * BK);
        // A: fp32 loads -> bf16 -> swizzled LDS
        const float4* s4 = (const float4*)(gA + kt * BK);
        float4 f[8];
#pragma unroll
        for (int p = 0; p < 8; ++p) f[p] = s4[p];
#pragma unroll
        for (int j = 0; j < 4; ++j) {
            const float4 a = f[2 * j], b = f[2 * j + 1];
            bf16x8 o;
            o[0] = (bf16_t)a.x; o[1] = (bf16_t)a.y; o[2] = (bf16_t)a.z; o[3] = (bf16_t)a.w;
            o[4] = (bf16_t)b.x; o[5] = (bf16_t)b.y; o[6] = (bf16_t)b.z; o[7] = (bf16_t)b.w;
            *(bf16x8*)(wArow + ((abase + j) ^ arm) * 8) = o;
        }
        asm volatile("s_waitcnt vmcnt(0)" ::: "memory");
        __syncthreads();
#pragma unroll
        for (int h = 0; h < 2; ++h) {
            const bf16_t* pa = h ? paB1 : paB0;
            const bf16_t* pb = h ? pbB1 : pbB0;
            bf16x8 af[4], bfv[4];
#pragma unroll
            for (int mt = 0; mt < 4; ++mt)
                af[mt] = *(const bf16x8*)(pa + mt * 16 * BK);
#pragma unroll
            for (int nt = 0; nt < 4; ++nt)
                bfv[nt] = *(const bf16x8*)(pb + nt * 16 * BK);
#pragma unroll
            for (int mt = 0; mt < 4; ++mt)
#pragma unroll
                for (int nt = 0; nt < 4; ++nt)
                    acc[mt][nt] = __builtin_amdgcn_mfma_f32_16x16x32_bf16(
                        af[mt], bfv[nt], acc[mt][nt], 0, 0, 0);
        }
        __syncthreads();
    }

    const int r0 = m0 + wr * 64 + (lane >> 4) * 4;
    const int c0 = n0 + wc * 64 + (lane & 15);
#pragma unroll
    for (int mt = 0; mt < 4; ++mt)
#pragma unroll
        for (int nt = 0; nt < 4; ++nt) {
            const int col = c0 + nt * 16;
            const float bb = bias[col];
#pragma unroll
            for (int r = 0; r < 4; ++r) {
                const int row = r0 + mt * 16 + r;
                C[(long)row * D_DIM + col] = (bf16_t)(acc[mt][nt][r] + bb);
            }
        }
}

// scores = (WQ @ WK^T) / 32, causal: only tiles tj<=ti computed. bf16 out.
__global__ __launch_bounds__(256) void k_gemm_scores(
    const bf16_t* __restrict__ PrQ, const bf16_t* __restrict__ PrK,
    bf16_t* __restrict__ SC)
{
    const int ti = blockIdx.y, tj = blockIdx.x, b = blockIdx.z;
    if (tj > ti) return;  // fully-masked tile: never read downstream
    const bf16_t* A  = PrQ + (long)b * S_LEN * D_DIM;
    const bf16_t* Bt = PrK + (long)b * S_LEN * D_DIM;
    bf16_t* C        = SC  + (long)b * S_LEN * S_LEN;
    const int m0 = ti * BM, n0 = tj * BN;
    f32x4 acc[4][4];
    gemm_bt_core(A, Bt, D_DIM, D_DIM, m0, n0, D_DIM / BK, acc);
    const int lane = threadIdx.x & 63, w = threadIdx.x >> 6;
    const int wr = w >> 1, wc = w & 1;
    const int r0 = m0 + wr * 64 + (lane >> 4) * 4;
    const int c0 = n0 + wc * 64 + (lane & 15);
#pragma unroll
    for (int mt = 0; mt < 4; ++mt)
#pragma unroll
        for (int nt = 0; nt < 4; ++nt) {
            const int col = c0 + nt * 16;
#pragma unroll
            for (int r = 0; r < 4; ++r) {
                const int row = r0 + mt * 16 + r;
                C[(long)row * S_LEN + col] = (bf16_t)(acc[mt][nt][r] * 0.03125f);
            }
        }
}

// causal softmax, wave-per-row, register-resident, shuffle reductions.
__global__ __launch_bounds__(256) void k_softmax(bf16_t* __restrict__ SC)
{
    const int w = threadIdx.x >> 6, lane = threadIdx.x & 63;
    const int i = blockIdx.x * 4 + w;
    const int b = blockIdx.y;
    bf16_t* row = SC + ((long)b * S_LEN + i) * S_LEN;
    const int n    = i + 1;
    const int jend = ((i >> 7) + 1) << 7;
    const int nch  = (jend + 511) >> 9;     // 512-elem chunks to touch (1..4)
    float x[4][8];
    float mx = -1e30f;
#pragma unroll
    for (int c = 0; c < 4; ++c) {
        if (c < nch) {
            bf16x8 vv = *(const bf16x8*)(row + c * 512 + lane * 8);
#pragma unroll
            for (int e = 0; e < 8; ++e) {
                const int j = c * 512 + lane * 8 + e;
                const float f = (j < n) ? (float)vv[e] : -1e30f;
                x[c][e] = f;
                mx = fmaxf(mx, f);
            }
        }
    }
#pragma unroll
    for (int d = 1; d < 64; d <<= 1) mx = fmaxf(mx, __shfl_xor(mx, d, 64));
    float sm = 0.f;
#pragma unroll
    for (int c = 0; c < 4; ++c) {
        if (c < nch) {
#pragma unroll
            for (int e = 0; e < 8; ++e) {
                const int j = c * 512 + lane * 8 + e;
                float p = (j < n) ? __expf(x[c][e] - mx) : 0.f;
                x[c][e] = p;
                sm += p;
            }
        }
    }
#pragma unroll
    for (int d = 1; d < 64; d <<= 1) sm += __shfl_xor(sm, d, 64);
    const float inv = 1.0f / sm;
#pragma unroll
    for (int c = 0; c < 4; ++c) {
        if (c < nch) {
            bf16x8 o;
#pragma unroll
            for (int e = 0; e < 8; ++e) o[e] = (bf16_t)(x[c][e] * inv);
            *(bf16x8*)(row + c * 512 + lane * 8) = o;
        }
    }
}

// out = P @ WVt^T, fp32 out; K-loop truncated at diagonal tile. Heavy-first.
__global__ __launch_bounds__(256) void k_gemm_pv(
    const bf16_t* __restrict__ SC, const bf16_t* __restrict__ WVt,
    float* __restrict__ Out)
{
    const int ti = (S_LEN / BM - 1) - blockIdx.y, b = blockIdx.z;
    const bf16_t* A  = SC  + (long)b * S_LEN * S_LEN;
    const bf16_t* Bt = WVt + (long)b * D_DIM * S_LEN;
    float* C         = Out + (long)b * S_LEN * D_DIM;
    const int m0 = ti * BM, n0 = blockIdx.x * BN;
    f32x4 acc[4][4];
    gemm_bt_core(A, Bt, S_LEN, S_LEN, m0, n0, (ti + 1) * (BM / BK), acc);
    const int lane = threadIdx.x & 63, w = threadIdx.x >> 6;
    const int wr = w >> 1, wc = w & 1;
    const int r0 = m0 + wr * 64 + (lane >> 4) * 4;
    const int c0 = n0 + wc * 64 + (lane & 15);
#pragma unroll
    for (int mt = 0; mt < 4; ++mt)
#pragma unroll
        for (int nt = 0; nt < 4; ++nt) {
            const int col = c0 + nt * 16;
#pragma unroll
            for (int r = 0; r < 4; ++r) {
                const int row = r0 + mt * 16 + r;
                C[(long)row * D_DIM + col] = acc[mt][nt][r];
            }
        }
}

extern "C" void kernel_launch(void* const* d_in, const int* in_sizes, int n_in,
                              void* d_out, int out_size, void* d_ws, size_t ws_size,
                              hipStream_t stream)
{
    (void)in_sizes; (void)n_in; (void)out_size; (void)ws_size;
    const float* q  = (const float*)d_in[0];
    const float* k  = (const float*)d_in[1];
    const float* v  = (const float*)d_in[2];
    // d_in[3] = mask: causal triu(1) — applied analytically
    const float* Wq = (const float*)d_in[4];
    const float* bq = (const float*)d_in[5];
    const float* Wk = (const float*)d_in[6];
    const float* bk = (const float*)d_in[7];
    const float* Wv = (const float*)d_in[8];
    const float* bv = (const float*)d_in[9];
    float* out = (float*)d_out;

    // ws layout (bf16 elems): Wt[3*D*D] | SC[B*S*S] | Pr[3*B*S*D] | WVt[B*D*S]
    bf16_t* ws = (bf16_t*)d_ws;
    const long nW = (long)D_DIM * D_DIM;           // 1,048,576
    const long nX = (long)NB * S_LEN * D_DIM;      // 8,388,608
    bf16_t* Wt  = ws;
    bf16_t* SC  = Wt + 3 * nW;
    bf16_t* Pr  = SC + 3 * nX;     // keep prior offsets (SC slot sized 3*nX)
    bf16_t* WVt = Pr + 3 * nX;
    bf16_t* PrQ = Pr;
    bf16_t* PrK = Pr + nX;
    bf16_t* PrV = Pr + 2 * nX;

    k_tw         <<<dim3(32, 32, 3),    dim3(32,8), 0, stream>>>(Wq, Wk, Wv, Wt);
    k_gemm_proj  <<<dim3(64, 8, 3),     256,        0, stream>>>(q, k, v, Wt, bq, bk, bv, Pr);
    k_tv         <<<dim3(32, 64, NB),   dim3(32,8), 0, stream>>>(PrV, WVt);
    k_gemm_scores<<<dim3(16, 16, NB),   256,        0, stream>>>(PrQ, PrK, SC);
    k_softmax    <<<dim3(S_LEN / 4, NB),256,        0, stream>>>(SC);
    k_gemm_pv    <<<dim3(8, 16, NB),    256,        0, stream>>>(SC, WVt, out);
}

// Round 5
// 339.597 us; speedup vs baseline: 1.1047x; 1.1047x over previous
//
#include <hip/hip_runtime.h>
#include <math.h>

#define S_LEN 2048
#define D_DIM 1024
#define NB    4

typedef __bf16 bf16_t;
typedef __bf16 bf16x8 __attribute__((ext_vector_type(8)));
typedef float  f32x4  __attribute__((ext_vector_type(4)));

#define BM 128
#define BN 128
#define BK 64   // 64 bf16 = 128 B per row

// async global->LDS, 16B per lane; lds ptr must be wave-uniform base (HW adds lane*16)
__device__ __forceinline__ void async16(const void* g, void* l) {
    __builtin_amdgcn_global_load_lds(
        (__attribute__((address_space(1))) const void*)g,
        (__attribute__((address_space(3))) void*)l, 16, 0, 0);
}

// C[128x128] tile of A[M,K] * Bt[N,K]^T, bf16 in, fp32 acc.
// BK=64 2-barrier K-loop. LDS bank swizzle: row r's 16B k-block kb stored at
// slot kb ^ (r&7); each 16-lane ds_read_b128 phase covers all 8 bank groups 2x.
__device__ __forceinline__ void gemm_bt_core(
    const bf16_t* __restrict__ A, const bf16_t* __restrict__ Bt,
    int lda, int ldb, int m0, int n0, int kTiles, f32x4 (&acc)[4][4])
{
    __shared__ bf16_t lA[BM * BK];   // 16 KB
    __shared__ bf16_t lB[BN * BK];   // 16 KB
    const int t    = threadIdx.x;
    const int w    = t >> 6;               // wave 0..3
    const int lane = t & 63;
    const int wr   = w >> 1, wc = w & 1;   // 2x2 wave grid, each wave 64x64
    const int srow   = lane >> 3;                       // 0..7
    const int kb_src = ((lane & 7) ^ (lane >> 3)) * 8;  // bf16 offset in row
    const int fr = lane & 15, fq = lane >> 4;
    const int fof0 = (((0 * 4 + fq) ^ (fr & 7)) * 8);
    const int fof1 = (((1 * 4 + fq) ^ (fr & 7)) * 8);
    const bf16_t* paB0 = lA + (wr * 64 + fr) * BK + fof0;
    const bf16_t* paB1 = lA + (wr * 64 + fr) * BK + fof1;
    const bf16_t* pbB0 = lB + (wc * 64 + fr) * BK + fof0;
    const bf16_t* pbB1 = lB + (wc * 64 + fr) * BK + fof1;
    bf16_t* ldsA = lA + (w * 32) * BK;
    bf16_t* ldsB = lB + (w * 32) * BK;
    const bf16_t* gA = A  + (long)(m0 + w * 32 + srow) * lda + kb_src;
    const bf16_t* gB = Bt + (long)(n0 + w * 32 + srow) * ldb + kb_src;

#pragma unroll
    for (int mt = 0; mt < 4; ++mt)
#pragma unroll
        for (int nt = 0; nt < 4; ++nt)
            acc[mt][nt] = f32x4{0.f, 0.f, 0.f, 0.f};

    for (int kt = 0; kt < kTiles; ++kt) {
        const long k0 = (long)kt * BK;
#pragma unroll
        for (int i = 0; i < 4; ++i) {
            async16(gA + k0 + (long)(i * 8) * lda, ldsA + i * 8 * BK);
            async16(gB + k0 + (long)(i * 8) * ldb, ldsB + i * 8 * BK);
        }
        asm volatile("s_waitcnt vmcnt(0)" ::: "memory");
        __syncthreads();
#pragma unroll
        for (int h = 0; h < 2; ++h) {
            const bf16_t* pa = h ? paB1 : paB0;
            const bf16_t* pb = h ? pbB1 : pbB0;
            bf16x8 af[4], bfv[4];
#pragma unroll
            for (int mt = 0; mt < 4; ++mt)
                af[mt] = *(const bf16x8*)(pa + mt * 16 * BK);
#pragma unroll
            for (int nt = 0; nt < 4; ++nt)
                bfv[nt] = *(const bf16x8*)(pb + nt * 16 * BK);
#pragma unroll
            for (int mt = 0; mt < 4; ++mt)
#pragma unroll
                for (int nt = 0; nt < 4; ++nt)
                    acc[mt][nt] = __builtin_amdgcn_mfma_f32_16x16x32_bf16(
                        af[mt], bfv[nt], acc[mt][nt], 0, 0, 0);
        }
        __syncthreads();
    }
}

// q/k/v fp32 -> bf16, vectorized (8 elems/thread)
__global__ __launch_bounds__(256) void k_f2b(
    const float* __restrict__ q, const float* __restrict__ k,
    const float* __restrict__ v, bf16_t* __restrict__ Xb)
{
    const int z = blockIdx.z;
    const float* src = (z == 0) ? q : ((z == 1) ? k : v);
    bf16_t* dst = Xb + (long)z * ((long)NB * S_LEN * D_DIM);
    const long i = (long)blockIdx.x * blockDim.x + threadIdx.x;
    const float4* s4 = (const float4*)src;
    float4 a = s4[2 * i], c = s4[2 * i + 1];
    bf16x8 o;
    o[0] = (bf16_t)a.x; o[1] = (bf16_t)a.y; o[2] = (bf16_t)a.z; o[3] = (bf16_t)a.w;
    o[4] = (bf16_t)c.x; o[5] = (bf16_t)c.y; o[6] = (bf16_t)c.z; o[7] = (bf16_t)c.w;
    *(bf16x8*)(dst + i * 8) = o;
}

// W [K,N] fp32 -> Wt [N,K] bf16 (transpose+cast), 32x32 LDS tiles
__global__ __launch_bounds__(256) void k_tw(
    const float* __restrict__ Wq, const float* __restrict__ Wk,
    const float* __restrict__ Wv, bf16_t* __restrict__ Wt)
{
    __shared__ float tile[32][33];
    const int z = blockIdx.z;
    const float* W = (z == 0) ? Wq : ((z == 1) ? Wk : Wv);
    bf16_t* T = Wt + (long)z * D_DIM * D_DIM;
    const int tx = threadIdx.x, ty = threadIdx.y;
    const int x  = blockIdx.x * 32 + tx;   // n
    const int y0 = blockIdx.y * 32;        // k
#pragma unroll
    for (int j = ty; j < 32; j += 8) tile[j][tx] = W[(long)(y0 + j) * D_DIM + x];
    __syncthreads();
    const int x2 = blockIdx.y * 32 + tx;   // k
    const int y2 = blockIdx.x * 32;        // n
#pragma unroll
    for (int j = ty; j < 32; j += 8)
        T[(long)(y2 + j) * D_DIM + x2] = (bf16_t)tile[tx][j];
}

// WV [S,D] bf16 -> WVt [D,S] bf16 per batch
__global__ __launch_bounds__(256) void k_tv(
    const bf16_t* __restrict__ PrV, bf16_t* __restrict__ WVt)
{
    __shared__ bf16_t tile[32][33];
    const int b = blockIdx.z;
    const bf16_t* src = PrV + (long)b * S_LEN * D_DIM;
    bf16_t* dst = WVt + (long)b * D_DIM * S_LEN;
    const int tx = threadIdx.x, ty = threadIdx.y;
    const int x  = blockIdx.x * 32 + tx;   // d
    const int y0 = blockIdx.y * 32;        // s
#pragma unroll
    for (int j = ty; j < 32; j += 8) tile[j][tx] = src[(long)(y0 + j) * D_DIM + x];
    __syncthreads();
    const int x2 = blockIdx.y * 32 + tx;   // s
    const int y2 = blockIdx.x * 32;        // d
#pragma unroll
    for (int j = ty; j < 32; j += 8)
        dst[(long)(y2 + j) * S_LEN + x2] = tile[tx][j];
}

// One projection: Pr = Xb @ Wt^T + bias, bf16 out. One dispatch per tensor
// (split from grid-z so rocprof top-5 can surface the non-proj kernels).
__global__ __launch_bounds__(256) void k_gemm_proj(
    const bf16_t* __restrict__ A, const bf16_t* __restrict__ Bt,
    const float* __restrict__ bias, bf16_t* __restrict__ C)
{
    const int m0 = blockIdx.x * BM, n0 = blockIdx.y * BN;
    f32x4 acc[4][4];
    gemm_bt_core(A, Bt, D_DIM, D_DIM, m0, n0, D_DIM / BK, acc);
    const int lane = threadIdx.x & 63, w = threadIdx.x >> 6;
    const int wr = w >> 1, wc = w & 1;
    const int r0 = m0 + wr * 64 + (lane >> 4) * 4;
    const int c0 = n0 + wc * 64 + (lane & 15);
#pragma unroll
    for (int mt = 0; mt < 4; ++mt)
#pragma unroll
        for (int nt = 0; nt < 4; ++nt) {
            const int col = c0 + nt * 16;
            const float bb = bias[col];
#pragma unroll
            for (int r = 0; r < 4; ++r) {
                const int row = r0 + mt * 16 + r;
                C[(long)row * D_DIM + col] = (bf16_t)(acc[mt][nt][r] + bb);
            }
        }
}

// scores = (WQ @ WK^T) / 32, causal: only tiles tj<=ti computed. bf16 out.
__global__ __launch_bounds__(256) void k_gemm_scores(
    const bf16_t* __restrict__ PrQ, const bf16_t* __restrict__ PrK,
    bf16_t* __restrict__ SC)
{
    const int ti = blockIdx.y, tj = blockIdx.x, b = blockIdx.z;
    if (tj > ti) return;  // fully-masked tile: never read downstream
    const bf16_t* A  = PrQ + (long)b * S_LEN * D_DIM;
    const bf16_t* Bt = PrK + (long)b * S_LEN * D_DIM;
    bf16_t* C        = SC  + (long)b * S_LEN * S_LEN;
    const int m0 = ti * BM, n0 = tj * BN;
    f32x4 acc[4][4];
    gemm_bt_core(A, Bt, D_DIM, D_DIM, m0, n0, D_DIM / BK, acc);
    const int lane = threadIdx.x & 63, w = threadIdx.x >> 6;
    const int wr = w >> 1, wc = w & 1;
    const int r0 = m0 + wr * 64 + (lane >> 4) * 4;
    const int c0 = n0 + wc * 64 + (lane & 15);
#pragma unroll
    for (int mt = 0; mt < 4; ++mt)
#pragma unroll
        for (int nt = 0; nt < 4; ++nt) {
            const int col = c0 + nt * 16;
#pragma unroll
            for (int r = 0; r < 4; ++r) {
                const int row = r0 + mt * 16 + r;
                C[(long)row * S_LEN + col] = (bf16_t)(acc[mt][nt][r] * 0.03125f);
            }
        }
}

// causal softmax, wave-per-row, register-resident, shuffle reductions.
__global__ __launch_bounds__(256) void k_softmax(bf16_t* __restrict__ SC)
{
    const int w = threadIdx.x >> 6, lane = threadIdx.x & 63;
    const int i = blockIdx.x * 4 + w;
    const int b = blockIdx.y;
    bf16_t* row = SC + ((long)b * S_LEN + i) * S_LEN;
    const int n    = i + 1;
    const int jend = ((i >> 7) + 1) << 7;
    const int nch  = (jend + 511) >> 9;     // 512-elem chunks to touch (1..4)
    float x[4][8];
    float mx = -1e30f;
#pragma unroll
    for (int c = 0; c < 4; ++c) {
        if (c < nch) {
            bf16x8 vv = *(const bf16x8*)(row + c * 512 + lane * 8);
#pragma unroll
            for (int e = 0; e < 8; ++e) {
                const int j = c * 512 + lane * 8 + e;
                const float f = (j < n) ? (float)vv[e] : -1e30f;
                x[c][e] = f;
                mx = fmaxf(mx, f);
            }
        }
    }
#pragma unroll
    for (int d = 1; d < 64; d <<= 1) mx = fmaxf(mx, __shfl_xor(mx, d, 64));
    float sm = 0.f;
#pragma unroll
    for (int c = 0; c < 4; ++c) {
        if (c < nch) {
#pragma unroll
            for (int e = 0; e < 8; ++e) {
                const int j = c * 512 + lane * 8 + e;
                float p = (j < n) ? __expf(x[c][e] - mx) : 0.f;
                x[c][e] = p;
                sm += p;
            }
        }
    }
#pragma unroll
    for (int d = 1; d < 64; d <<= 1) sm += __shfl_xor(sm, d, 64);
    const float inv = 1.0f / sm;
#pragma unroll
    for (int c = 0; c < 4; ++c) {
        if (c < nch) {
            bf16x8 o;
#pragma unroll
            for (int e = 0; e < 8; ++e) o[e] = (bf16_t)(x[c][e] * inv);
            *(bf16x8*)(row + c * 512 + lane * 8) = o;
        }
    }
}

// out = P @ WVt^T, fp32 out; K-loop truncated at diagonal tile. Heavy-first.
__global__ __launch_bounds__(256) void k_gemm_pv(
    const bf16_t* __restrict__ SC, const bf16_t* __restrict__ WVt,
    float* __restrict__ Out)
{
    const int ti = (S_LEN / BM - 1) - blockIdx.y, b = blockIdx.z;
    const bf16_t* A  = SC  + (long)b * S_LEN * S_LEN;
    const bf16_t* Bt = WVt + (long)b * D_DIM * S_LEN;
    float* C         = Out + (long)b * S_LEN * D_DIM;
    const int m0 = ti * BM, n0 = blockIdx.x * BN;
    f32x4 acc[4][4];
    gemm_bt_core(A, Bt, S_LEN, S_LEN, m0, n0, (ti + 1) * (BM / BK), acc);
    const int lane = threadIdx.x & 63, w = threadIdx.x >> 6;
    const int wr = w >> 1, wc = w & 1;
    const int r0 = m0 + wr * 64 + (lane >> 4) * 4;
    const int c0 = n0 + wc * 64 + (lane & 15);
#pragma unroll
    for (int mt = 0; mt < 4; ++mt)
#pragma unroll
        for (int nt = 0; nt < 4; ++nt) {
            const int col = c0 + nt * 16;
#pragma unroll
            for (int r = 0; r < 4; ++r) {
                const int row = r0 + mt * 16 + r;
                C[(long)row * D_DIM + col] = acc[mt][nt][r];
            }
        }
}

extern "C" void kernel_launch(void* const* d_in, const int* in_sizes, int n_in,
                              void* d_out, int out_size, void* d_ws, size_t ws_size,
                              hipStream_t stream)
{
    (void)in_sizes; (void)n_in; (void)out_size; (void)ws_size;
    const float* q  = (const float*)d_in[0];
    const float* k  = (const float*)d_in[1];
    const float* v  = (const float*)d_in[2];
    // d_in[3] = mask: causal triu(1) — applied analytically
    const float* Wq = (const float*)d_in[4];
    const float* bq = (const float*)d_in[5];
    const float* Wk = (const float*)d_in[6];
    const float* bk = (const float*)d_in[7];
    const float* Wv = (const float*)d_in[8];
    const float* bv = (const float*)d_in[9];
    float* out = (float*)d_out;

    // ws layout (bf16 elems): Wt[3*D*D] | Xb[3*B*S*D] (reused as SC[B*S*S]) | Pr[3*B*S*D] | WVt[B*D*S]
    bf16_t* ws = (bf16_t*)d_ws;
    const long nW = (long)D_DIM * D_DIM;           // 1,048,576
    const long nX = (long)NB * S_LEN * D_DIM;      // 8,388,608
    bf16_t* Wt  = ws;
    bf16_t* Xb  = Wt + 3 * nW;
    bf16_t* SC  = Xb;              // aliases Xb: Xb dead after projections
    bf16_t* Pr  = Xb + 3 * nX;
    bf16_t* WVt = Pr + 3 * nX;
    bf16_t* PrQ = Pr;
    bf16_t* PrK = Pr + nX;
    bf16_t* PrV = Pr + 2 * nX;

    k_f2b        <<<dim3(4096, 1, 3),   256,        0, stream>>>(q, k, v, Xb);
    k_tw         <<<dim3(32, 32, 3),    dim3(32,8), 0, stream>>>(Wq, Wk, Wv, Wt);
    k_gemm_proj  <<<dim3(64, 8),        256,        0, stream>>>(Xb,          Wt,          bq, PrQ);
    k_gemm_proj  <<<dim3(64, 8),        256,        0, stream>>>(Xb + nX,     Wt + nW,     bk, PrK);
    k_gemm_proj  <<<dim3(64, 8),        256,        0, stream>>>(Xb + 2 * nX, Wt + 2 * nW, bv, PrV);
    k_tv         <<<dim3(32, 64, NB),   dim3(32,8), 0, stream>>>(PrV, WVt);
    k_gemm_scores<<<dim3(16, 16, NB),   256,        0, stream>>>(PrQ, PrK, SC);
    k_softmax    <<<dim3(S_LEN / 4, NB),256,        0, stream>>>(SC);
    k_gemm_pv    <<<dim3(8, 16, NB),    256,        0, stream>>>(SC, WVt, out);
}

// Round 6
// 329.681 us; speedup vs baseline: 1.1379x; 1.0301x over previous
//
#include <hip/hip_runtime.h>
#include <math.h>

#define S_LEN 2048
#define D_DIM 1024
#define NB    4

typedef __bf16 bf16_t;
typedef __bf16 bf16x8 __attribute__((ext_vector_type(8)));
typedef float  f32x4  __attribute__((ext_vector_type(4)));

#define BM 128
#define BN 128
#define BK 64   // 64 bf16 = 128 B per row

// async global->LDS, 16B per lane; lds ptr must be wave-uniform base (HW adds lane*16)
__device__ __forceinline__ void async16(const void* g, void* l) {
    __builtin_amdgcn_global_load_lds(
        (__attribute__((address_space(1))) const void*)g,
        (__attribute__((address_space(3))) void*)l, 16, 0, 0);
}

// C[128x128] tile of A[M,K] * Bt[N,K]^T, bf16 in, fp32 acc.
// BK=64 2-barrier K-loop. LDS bank swizzle: row r's 16B k-block kb stored at
// slot kb ^ (r&7); each 16-lane ds_read_b128 phase covers all 8 bank groups 2x.
__device__ __forceinline__ void gemm_bt_core(
    const bf16_t* __restrict__ A, const bf16_t* __restrict__ Bt,
    int lda, int ldb, int m0, int n0, int kTiles, f32x4 (&acc)[4][4])
{
    __shared__ bf16_t lA[BM * BK];   // 16 KB
    __shared__ bf16_t lB[BN * BK];   // 16 KB
    const int t    = threadIdx.x;
    const int w    = t >> 6;               // wave 0..3
    const int lane = t & 63;
    const int wr   = w >> 1, wc = w & 1;   // 2x2 wave grid, each wave 64x64
    const int srow   = lane >> 3;                       // 0..7
    const int kb_src = ((lane & 7) ^ (lane >> 3)) * 8;  // bf16 offset in row
    const int fr = lane & 15, fq = lane >> 4;
    const int fof0 = (((0 * 4 + fq) ^ (fr & 7)) * 8);
    const int fof1 = (((1 * 4 + fq) ^ (fr & 7)) * 8);
    const bf16_t* paB0 = lA + (wr * 64 + fr) * BK + fof0;
    const bf16_t* paB1 = lA + (wr * 64 + fr) * BK + fof1;
    const bf16_t* pbB0 = lB + (wc * 64 + fr) * BK + fof0;
    const bf16_t* pbB1 = lB + (wc * 64 + fr) * BK + fof1;
    bf16_t* ldsA = lA + (w * 32) * BK;
    bf16_t* ldsB = lB + (w * 32) * BK;
    const bf16_t* gA = A  + (long)(m0 + w * 32 + srow) * lda + kb_src;
    const bf16_t* gB = Bt + (long)(n0 + w * 32 + srow) * ldb + kb_src;

#pragma unroll
    for (int mt = 0; mt < 4; ++mt)
#pragma unroll
        for (int nt = 0; nt < 4; ++nt)
            acc[mt][nt] = f32x4{0.f, 0.f, 0.f, 0.f};

    for (int kt = 0; kt < kTiles; ++kt) {
        const long k0 = (long)kt * BK;
#pragma unroll
        for (int i = 0; i < 4; ++i) {
            async16(gA + k0 + (long)(i * 8) * lda, ldsA + i * 8 * BK);
            async16(gB + k0 + (long)(i * 8) * ldb, ldsB + i * 8 * BK);
        }
        asm volatile("s_waitcnt vmcnt(0)" ::: "memory");
        __syncthreads();
#pragma unroll
        for (int h = 0; h < 2; ++h) {
            const bf16_t* pa = h ? paB1 : paB0;
            const bf16_t* pb = h ? pbB1 : pbB0;
            bf16x8 af[4], bfv[4];
#pragma unroll
            for (int mt = 0; mt < 4; ++mt)
                af[mt] = *(const bf16x8*)(pa + mt * 16 * BK);
#pragma unroll
            for (int nt = 0; nt < 4; ++nt)
                bfv[nt] = *(const bf16x8*)(pb + nt * 16 * BK);
#pragma unroll
            for (int mt = 0; mt < 4; ++mt)
#pragma unroll
                for (int nt = 0; nt < 4; ++nt)
                    acc[mt][nt] = __builtin_amdgcn_mfma_f32_16x16x32_bf16(
                        af[mt], bfv[nt], acc[mt][nt], 0, 0, 0);
        }
        __syncthreads();
    }
}

// q/k/v fp32 -> bf16, vectorized (8 elems/thread)
__global__ __launch_bounds__(256) void k_f2b(
    const float* __restrict__ q, const float* __restrict__ k,
    const float* __restrict__ v, bf16_t* __restrict__ Xb)
{
    const int z = blockIdx.z;
    const float* src = (z == 0) ? q : ((z == 1) ? k : v);
    bf16_t* dst = Xb + (long)z * ((long)NB * S_LEN * D_DIM);
    const long i = (long)blockIdx.x * blockDim.x + threadIdx.x;
    const float4* s4 = (const float4*)src;
    float4 a = s4[2 * i], c = s4[2 * i + 1];
    bf16x8 o;
    o[0] = (bf16_t)a.x; o[1] = (bf16_t)a.y; o[2] = (bf16_t)a.z; o[3] = (bf16_t)a.w;
    o[4] = (bf16_t)c.x; o[5] = (bf16_t)c.y; o[6] = (bf16_t)c.z; o[7] = (bf16_t)c.w;
    *(bf16x8*)(dst + i * 8) = o;
}

// W [K,N] fp32 -> Wt [N,K] bf16 (transpose+cast), 32x32 LDS tiles
__global__ __launch_bounds__(256) void k_tw(
    const float* __restrict__ Wq, const float* __restrict__ Wk,
    const float* __restrict__ Wv, bf16_t* __restrict__ Wt)
{
    __shared__ float tile[32][33];
    const int z = blockIdx.z;
    const float* W = (z == 0) ? Wq : ((z == 1) ? Wk : Wv);
    bf16_t* T = Wt + (long)z * D_DIM * D_DIM;
    const int tx = threadIdx.x, ty = threadIdx.y;
    const int x  = blockIdx.x * 32 + tx;   // n
    const int y0 = blockIdx.y * 32;        // k
#pragma unroll
    for (int j = ty; j < 32; j += 8) tile[j][tx] = W[(long)(y0 + j) * D_DIM + x];
    __syncthreads();
    const int x2 = blockIdx.y * 32 + tx;   // k
    const int y2 = blockIdx.x * 32;        // n
#pragma unroll
    for (int j = ty; j < 32; j += 8)
        T[(long)(y2 + j) * D_DIM + x2] = (bf16_t)tile[tx][j];
}

// WV [S,D] bf16 -> WVt [D,S] bf16 per batch
__global__ __launch_bounds__(256) void k_tv(
    const bf16_t* __restrict__ PrV, bf16_t* __restrict__ WVt)
{
    __shared__ bf16_t tile[32][33];
    const int b = blockIdx.z;
    const bf16_t* src = PrV + (long)b * S_LEN * D_DIM;
    bf16_t* dst = WVt + (long)b * D_DIM * S_LEN;
    const int tx = threadIdx.x, ty = threadIdx.y;
    const int x  = blockIdx.x * 32 + tx;   // d
    const int y0 = blockIdx.y * 32;        // s
#pragma unroll
    for (int j = ty; j < 32; j += 8) tile[j][tx] = src[(long)(y0 + j) * D_DIM + x];
    __syncthreads();
    const int x2 = blockIdx.y * 32 + tx;   // s
    const int y2 = blockIdx.x * 32;        // d
#pragma unroll
    for (int j = ty; j < 32; j += 8)
        dst[(long)(y2 + j) * S_LEN + x2] = tile[tx][j];
}

// Projections: Pr_z = Xb_z @ Wt_z^T + bias_z, bf16 out. Single fused dispatch
// (z in grid): 1536 blocks pipeline block-rounds; the 3x512 split cost ~12us.
__global__ __launch_bounds__(256) void k_gemm_proj(
    const bf16_t* __restrict__ Xb, const bf16_t* __restrict__ Wt,
    const float* __restrict__ bq, const float* __restrict__ bk,
    const float* __restrict__ bv, bf16_t* __restrict__ Pr)
{
    const int z = blockIdx.z;
    const bf16_t* A  = Xb + (long)z * ((long)NB * S_LEN * D_DIM);
    const bf16_t* Bt = Wt + (long)z * D_DIM * D_DIM;
    bf16_t* C        = Pr + (long)z * ((long)NB * S_LEN * D_DIM);
    const float* bias = (z == 0) ? bq : ((z == 1) ? bk : bv);
    const int m0 = blockIdx.x * BM, n0 = blockIdx.y * BN;
    f32x4 acc[4][4];
    gemm_bt_core(A, Bt, D_DIM, D_DIM, m0, n0, D_DIM / BK, acc);
    const int lane = threadIdx.x & 63, w = threadIdx.x >> 6;
    const int wr = w >> 1, wc = w & 1;
    const int r0 = m0 + wr * 64 + (lane >> 4) * 4;
    const int c0 = n0 + wc * 64 + (lane & 15);
#pragma unroll
    for (int mt = 0; mt < 4; ++mt)
#pragma unroll
        for (int nt = 0; nt < 4; ++nt) {
            const int col = c0 + nt * 16;
            const float bb = bias[col];
#pragma unroll
            for (int r = 0; r < 4; ++r) {
                const int row = r0 + mt * 16 + r;
                C[(long)row * D_DIM + col] = (bf16_t)(acc[mt][nt][r] + bb);
            }
        }
}

// scores = (WQ @ WK^T) / 32, causal. Triangular block enumeration: exactly
// 136 live blocks per batch (no dead tj>ti blocks poisoning occupancy).
__global__ __launch_bounds__(256) void k_gemm_scores(
    const bf16_t* __restrict__ PrQ, const bf16_t* __restrict__ PrK,
    bf16_t* __restrict__ SC)
{
    const int u = blockIdx.x, b = blockIdx.z;
    // u -> (ti, tj) with tj <= ti: ti = floor((sqrt(8u+1)-1)/2), fix up fp error
    int ti = (int)((sqrtf(8.0f * (float)u + 1.0f) - 1.0f) * 0.5f);
    while ((ti + 1) * (ti + 2) / 2 <= u) ++ti;
    while (ti * (ti + 1) / 2 > u) --ti;
    const int tj = u - ti * (ti + 1) / 2;
    const bf16_t* A  = PrQ + (long)b * S_LEN * D_DIM;
    const bf16_t* Bt = PrK + (long)b * S_LEN * D_DIM;
    bf16_t* C        = SC  + (long)b * S_LEN * S_LEN;
    const int m0 = ti * BM, n0 = tj * BN;
    f32x4 acc[4][4];
    gemm_bt_core(A, Bt, D_DIM, D_DIM, m0, n0, D_DIM / BK, acc);
    const int lane = threadIdx.x & 63, w = threadIdx.x >> 6;
    const int wr = w >> 1, wc = w & 1;
    const int r0 = m0 + wr * 64 + (lane >> 4) * 4;
    const int c0 = n0 + wc * 64 + (lane & 15);
#pragma unroll
    for (int mt = 0; mt < 4; ++mt)
#pragma unroll
        for (int nt = 0; nt < 4; ++nt) {
            const int col = c0 + nt * 16;
#pragma unroll
            for (int r = 0; r < 4; ++r) {
                const int row = r0 + mt * 16 + r;
                C[(long)row * S_LEN + col] = (bf16_t)(acc[mt][nt][r] * 0.03125f);
            }
        }
}

// causal softmax, wave-per-row, register-resident, shuffle reductions.
__global__ __launch_bounds__(256) void k_softmax(bf16_t* __restrict__ SC)
{
    const int w = threadIdx.x >> 6, lane = threadIdx.x & 63;
    const int i = blockIdx.x * 4 + w;
    const int b = blockIdx.y;
    bf16_t* row = SC + ((long)b * S_LEN + i) * S_LEN;
    const int n    = i + 1;
    const int jend = ((i >> 7) + 1) << 7;
    const int nch  = (jend + 511) >> 9;     // 512-elem chunks to touch (1..4)
    float x[4][8];
    float mx = -1e30f;
#pragma unroll
    for (int c = 0; c < 4; ++c) {
        if (c < nch) {
            bf16x8 vv = *(const bf16x8*)(row + c * 512 + lane * 8);
#pragma unroll
            for (int e = 0; e < 8; ++e) {
                const int j = c * 512 + lane * 8 + e;
                const float f = (j < n) ? (float)vv[e] : -1e30f;
                x[c][e] = f;
                mx = fmaxf(mx, f);
            }
        }
    }
#pragma unroll
    for (int d = 1; d < 64; d <<= 1) mx = fmaxf(mx, __shfl_xor(mx, d, 64));
    float sm = 0.f;
#pragma unroll
    for (int c = 0; c < 4; ++c) {
        if (c < nch) {
#pragma unroll
            for (int e = 0; e < 8; ++e) {
                const int j = c * 512 + lane * 8 + e;
                float p = (j < n) ? __expf(x[c][e] - mx) : 0.f;
                x[c][e] = p;
                sm += p;
            }
        }
    }
#pragma unroll
    for (int d = 1; d < 64; d <<= 1) sm += __shfl_xor(sm, d, 64);
    const float inv = 1.0f / sm;
#pragma unroll
    for (int c = 0; c < 4; ++c) {
        if (c < nch) {
            bf16x8 o;
#pragma unroll
            for (int e = 0; e < 8; ++e) o[e] = (bf16_t)(x[c][e] * inv);
            *(bf16x8*)(row + c * 512 + lane * 8) = o;
        }
    }
}

// out = P @ WVt^T, fp32 out; K-loop truncated at diagonal tile. Heavy-first.
__global__ __launch_bounds__(256) void k_gemm_pv(
    const bf16_t* __restrict__ SC, const bf16_t* __restrict__ WVt,
    float* __restrict__ Out)
{
    const int ti = (S_LEN / BM - 1) - blockIdx.y, b = blockIdx.z;
    const bf16_t* A  = SC  + (long)b * S_LEN * S_LEN;
    const bf16_t* Bt = WVt + (long)b * D_DIM * S_LEN;
    float* C         = Out + (long)b * S_LEN * D_DIM;
    const int m0 = ti * BM, n0 = blockIdx.x * BN;
    f32x4 acc[4][4];
    gemm_bt_core(A, Bt, S_LEN, S_LEN, m0, n0, (ti + 1) * (BM / BK), acc);
    const int lane = threadIdx.x & 63, w = threadIdx.x >> 6;
    const int wr = w >> 1, wc = w & 1;
    const int r0 = m0 + wr * 64 + (lane >> 4) * 4;
    const int c0 = n0 + wc * 64 + (lane & 15);
#pragma unroll
    for (int mt = 0; mt < 4; ++mt)
#pragma unroll
        for (int nt = 0; nt < 4; ++nt) {
            const int col = c0 + nt * 16;
#pragma unroll
            for (int r = 0; r < 4; ++r) {
                const int row = r0 + mt * 16 + r;
                C[(long)row * D_DIM + col] = acc[mt][nt][r];
            }
        }
}

extern "C" void kernel_launch(void* const* d_in, const int* in_sizes, int n_in,
                              void* d_out, int out_size, void* d_ws, size_t ws_size,
                              hipStream_t stream)
{
    (void)in_sizes; (void)n_in; (void)out_size; (void)ws_size;
    const float* q  = (const float*)d_in[0];
    const float* k  = (const float*)d_in[1];
    const float* v  = (const float*)d_in[2];
    // d_in[3] = mask: causal triu(1) — applied analytically
    const float* Wq = (const float*)d_in[4];
    const float* bq = (const float*)d_in[5];
    const float* Wk = (const float*)d_in[6];
    const float* bk = (const float*)d_in[7];
    const float* Wv = (const float*)d_in[8];
    const float* bv = (const float*)d_in[9];
    float* out = (float*)d_out;

    // ws layout (bf16 elems): Wt[3*D*D] | Xb[3*B*S*D] (reused as SC[B*S*S]) | Pr[3*B*S*D] | WVt[B*D*S]
    bf16_t* ws = (bf16_t*)d_ws;
    const long nW = (long)D_DIM * D_DIM;           // 1,048,576
    const long nX = (long)NB * S_LEN * D_DIM;      // 8,388,608
    bf16_t* Wt  = ws;
    bf16_t* Xb  = Wt + 3 * nW;
    bf16_t* SC  = Xb;              // aliases Xb: Xb dead after projections
    bf16_t* Pr  = Xb + 3 * nX;
    bf16_t* WVt = Pr + 3 * nX;
    bf16_t* PrQ = Pr;
    bf16_t* PrK = Pr + nX;
    bf16_t* PrV = Pr + 2 * nX;

    k_f2b        <<<dim3(4096, 1, 3),   256,        0, stream>>>(q, k, v, Xb);
    k_tw         <<<dim3(32, 32, 3),    dim3(32,8), 0, stream>>>(Wq, Wk, Wv, Wt);
    k_gemm_proj  <<<dim3(64, 8, 3),     256,        0, stream>>>(Xb, Wt, bq, bk, bv, Pr);
    k_tv         <<<dim3(32, 64, NB),   dim3(32,8), 0, stream>>>(PrV, WVt);
    k_gemm_scores<<<dim3(136, 1, NB),   256,        0, stream>>>(PrQ, PrK, SC);
    k_softmax    <<<dim3(S_LEN / 4, NB),256,        0, stream>>>(SC);
    k_gemm_pv    <<<dim3(8, 16, NB),    256,        0, stream>>>(SC, WVt, out);
}

// Round 7
// 316.201 us; speedup vs baseline: 1.1864x; 1.0426x over previous
//
#include <hip/hip_runtime.h>
#include <math.h>

#define S_LEN 2048
#define D_DIM 1024
#define NB    4

typedef __bf16 bf16_t;
typedef __bf16 bf16x8 __attribute__((ext_vector_type(8)));
typedef float  f32x4  __attribute__((ext_vector_type(4)));
typedef unsigned int   u32;
typedef unsigned short u16;
typedef unsigned int   u32x4 __attribute__((ext_vector_type(4)));

#define BM 128
#define BN 128
#define BK 64   // 64 bf16 = 128 B per row

__device__ __forceinline__ u16 f2b_bits(float x) {
    bf16_t h = (bf16_t)x;
    return *(u16*)&h;
}

// async global->LDS, 16B per lane; lds ptr must be wave-uniform base (HW adds lane*16)
__device__ __forceinline__ void async16(const void* g, void* l) {
    __builtin_amdgcn_global_load_lds(
        (__attribute__((address_space(1))) const void*)g,
        (__attribute__((address_space(3))) void*)l, 16, 0, 0);
}

// C[128x128] tile of A[M,K] * Bt[N,K]^T, bf16 in, fp32 acc.
// BK=64 2-barrier K-loop. LDS bank swizzle: row r's 16B k-block kb stored at
// slot kb ^ (r&7); each 16-lane ds_read_b128 phase covers all 8 bank groups 2x.
__device__ __forceinline__ void gemm_bt_core(
    const bf16_t* __restrict__ A, const bf16_t* __restrict__ Bt,
    int lda, int ldb, int m0, int n0, int kTiles, f32x4 (&acc)[4][4])
{
    __shared__ bf16_t lA[BM * BK];   // 16 KB
    __shared__ bf16_t lB[BN * BK];   // 16 KB
    const int t    = threadIdx.x;
    const int w    = t >> 6;               // wave 0..3
    const int lane = t & 63;
    const int wr   = w >> 1, wc = w & 1;   // 2x2 wave grid, each wave 64x64
    const int srow   = lane >> 3;                       // 0..7
    const int kb_src = ((lane & 7) ^ (lane >> 3)) * 8;  // bf16 offset in row
    const int fr = lane & 15, fq = lane >> 4;
    const int fof0 = (((0 * 4 + fq) ^ (fr & 7)) * 8);
    const int fof1 = (((1 * 4 + fq) ^ (fr & 7)) * 8);
    const bf16_t* paB0 = lA + (wr * 64 + fr) * BK + fof0;
    const bf16_t* paB1 = lA + (wr * 64 + fr) * BK + fof1;
    const bf16_t* pbB0 = lB + (wc * 64 + fr) * BK + fof0;
    const bf16_t* pbB1 = lB + (wc * 64 + fr) * BK + fof1;
    bf16_t* ldsA = lA + (w * 32) * BK;
    bf16_t* ldsB = lB + (w * 32) * BK;
    const bf16_t* gA = A  + (long)(m0 + w * 32 + srow) * lda + kb_src;
    const bf16_t* gB = Bt + (long)(n0 + w * 32 + srow) * ldb + kb_src;

#pragma unroll
    for (int mt = 0; mt < 4; ++mt)
#pragma unroll
        for (int nt = 0; nt < 4; ++nt)
            acc[mt][nt] = f32x4{0.f, 0.f, 0.f, 0.f};

    for (int kt = 0; kt < kTiles; ++kt) {
        const long k0 = (long)kt * BK;
#pragma unroll
        for (int i = 0; i < 4; ++i) {
            async16(gA + k0 + (long)(i * 8) * lda, ldsA + i * 8 * BK);
            async16(gB + k0 + (long)(i * 8) * ldb, ldsB + i * 8 * BK);
        }
        asm volatile("s_waitcnt vmcnt(0)" ::: "memory");
        __syncthreads();
#pragma unroll
        for (int h = 0; h < 2; ++h) {
            const bf16_t* pa = h ? paB1 : paB0;
            const bf16_t* pb = h ? pbB1 : pbB0;
            bf16x8 af[4], bfv[4];
#pragma unroll
            for (int mt = 0; mt < 4; ++mt)
                af[mt] = *(const bf16x8*)(pa + mt * 16 * BK);
#pragma unroll
            for (int nt = 0; nt < 4; ++nt)
                bfv[nt] = *(const bf16x8*)(pb + nt * 16 * BK);
#pragma unroll
            for (int mt = 0; mt < 4; ++mt)
#pragma unroll
                for (int nt = 0; nt < 4; ++nt)
                    acc[mt][nt] = __builtin_amdgcn_mfma_f32_16x16x32_bf16(
                        af[mt], bfv[nt], acc[mt][nt], 0, 0, 0);
        }
        __syncthreads();
    }
}

// q/k/v fp32 -> bf16; one float4 per thread (dense coalescing), 8B store
__global__ __launch_bounds__(256) void k_f2b(
    const float* __restrict__ q, const float* __restrict__ k,
    const float* __restrict__ v, bf16_t* __restrict__ Xb)
{
    const int z = blockIdx.z;
    const float* src = (z == 0) ? q : ((z == 1) ? k : v);
    bf16_t* dst = Xb + (long)z * ((long)NB * S_LEN * D_DIM);
    const long i = (long)blockIdx.x * blockDim.x + threadIdx.x;
    float4 a = ((const float4*)src)[i];
    u32 lo = (u32)f2b_bits(a.x) | ((u32)f2b_bits(a.y) << 16);
    u32 hi = (u32)f2b_bits(a.z) | ((u32)f2b_bits(a.w) << 16);
    ((uint2*)(dst))[i] = make_uint2(lo, hi);
}

// W [K=1024,N=1024] fp32 -> Wt [N,K] bf16. 64x64 tiles, vectorized I/O.
// LDS u32[64][33]: tile[k][n-pair], +1 pad col.
__global__ __launch_bounds__(256) void k_tw(
    const float* __restrict__ Wq, const float* __restrict__ Wk,
    const float* __restrict__ Wv, bf16_t* __restrict__ Wt)
{
    __shared__ u32 tile[64][33];
    const int z = blockIdx.z;
    const float* W = (z == 0) ? Wq : ((z == 1) ? Wk : Wv);
    bf16_t* T = Wt + (long)z * D_DIM * D_DIM;
    const int t = threadIdx.x;
    const int k0 = blockIdx.x * 64, n0 = blockIdx.y * 64;
    // load: 4 rounds, 16 threads/row (float4 each)
#pragma unroll
    for (int rr = 0; rr < 4; ++rr) {
        const int kr = (t >> 4) + rr * 16;
        const int nq = (t & 15) * 4;
        float4 f = *(const float4*)(W + (long)(k0 + kr) * D_DIM + n0 + nq);
        tile[kr][(nq >> 1)]     = (u32)f2b_bits(f.x) | ((u32)f2b_bits(f.y) << 16);
        tile[kr][(nq >> 1) + 1] = (u32)f2b_bits(f.z) | ((u32)f2b_bits(f.w) << 16);
    }
    __syncthreads();
    // store: 2 rounds, 8 threads/row, repack k-pairs, uint4 store
#pragma unroll
    for (int rr = 0; rr < 2; ++rr) {
        const int nr = (t >> 3) + rr * 32;
        const int j0 = (t & 7) * 4;
        u32x4 o;
#pragma unroll
        for (int jj = 0; jj < 4; ++jj) {
            const int j = j0 + jj;
            const u32 ua = tile[2 * j][nr >> 1];
            const u32 ub = tile[2 * j + 1][nr >> 1];
            const u32 lo = (nr & 1) ? (ua >> 16) : (ua & 0xffffu);
            const u32 hi = (nr & 1) ? (ub >> 16) : (ub & 0xffffu);
            o[jj] = lo | (hi << 16);
        }
        *(u32x4*)(T + (long)(n0 + nr) * D_DIM + k0 + 2 * j0) = o;
    }
}

// WV [S,D] bf16 -> WVt [D,S] bf16 per batch. 64x64 tiles, vectorized I/O.
// LDS u32[64][33]: tile[s][d-pair], +1 pad col.
__global__ __launch_bounds__(256) void k_tv(
    const bf16_t* __restrict__ PrV, bf16_t* __restrict__ WVt)
{
    __shared__ u32 tile[64][33];
    const int b = blockIdx.z;
    const bf16_t* src = PrV + (long)b * S_LEN * D_DIM;
    bf16_t* dst = WVt + (long)b * D_DIM * S_LEN;
    const int t = threadIdx.x;
    const int d0 = blockIdx.x * 64, s0 = blockIdx.y * 64;
    // load: 2 rounds, 8 threads/row (bf16x8 = 4 u32 each)
#pragma unroll
    for (int rr = 0; rr < 2; ++rr) {
        const int sr = (t >> 3) + rr * 32;
        const int dp0 = (t & 7) * 4;     // d-pair index base
        u32x4 u = *(const u32x4*)(src + (long)(s0 + sr) * D_DIM + d0 + 2 * dp0);
#pragma unroll
        for (int q = 0; q < 4; ++q) tile[sr][dp0 + q] = u[q];
    }
    __syncthreads();
    // store: 2 rounds, 8 threads/row of dst, repack s-pairs, uint4 store
#pragma unroll
    for (int rr = 0; rr < 2; ++rr) {
        const int dr = (t >> 3) + rr * 32;
        const int j0 = (t & 7) * 4;      // s-pair index base
        u32x4 o;
#pragma unroll
        for (int jj = 0; jj < 4; ++jj) {
            const int j = j0 + jj;
            const u32 ua = tile[2 * j][dr >> 1];
            const u32 ub = tile[2 * j + 1][dr >> 1];
            const u32 lo = (dr & 1) ? (ua >> 16) : (ua & 0xffffu);
            const u32 hi = (dr & 1) ? (ub >> 16) : (ub & 0xffffu);
            o[jj] = lo | (hi << 16);
        }
        *(u32x4*)(dst + (long)(d0 + dr) * S_LEN + s0 + 2 * j0) = o;
    }
}

// Projections: Pr_z = Xb_z @ Wt_z^T + bias_z, bf16 out. Single fused dispatch.
__global__ __launch_bounds__(256) void k_gemm_proj(
    const bf16_t* __restrict__ Xb, const bf16_t* __restrict__ Wt,
    const float* __restrict__ bq, const float* __restrict__ bk,
    const float* __restrict__ bv, bf16_t* __restrict__ Pr)
{
    const int z = blockIdx.z;
    const bf16_t* A  = Xb + (long)z * ((long)NB * S_LEN * D_DIM);
    const bf16_t* Bt = Wt + (long)z * D_DIM * D_DIM;
    bf16_t* C        = Pr + (long)z * ((long)NB * S_LEN * D_DIM);
    const float* bias = (z == 0) ? bq : ((z == 1) ? bk : bv);
    const int m0 = blockIdx.x * BM, n0 = blockIdx.y * BN;
    f32x4 acc[4][4];
    gemm_bt_core(A, Bt, D_DIM, D_DIM, m0, n0, D_DIM / BK, acc);
    const int lane = threadIdx.x & 63, w = threadIdx.x >> 6;
    const int wr = w >> 1, wc = w & 1;
    const int r0 = m0 + wr * 64 + (lane >> 4) * 4;
    const int c0 = n0 + wc * 64 + (lane & 15);
#pragma unroll
    for (int mt = 0; mt < 4; ++mt)
#pragma unroll
        for (int nt = 0; nt < 4; ++nt) {
            const int col = c0 + nt * 16;
            const float bb = bias[col];
#pragma unroll
            for (int r = 0; r < 4; ++r) {
                const int row = r0 + mt * 16 + r;
                C[(long)row * D_DIM + col] = (bf16_t)(acc[mt][nt][r] + bb);
            }
        }
}

// scores = (WQ @ WK^T) / 32, causal, triangular block enumeration.
__global__ __launch_bounds__(256) void k_gemm_scores(
    const bf16_t* __restrict__ PrQ, const bf16_t* __restrict__ PrK,
    bf16_t* __restrict__ SC)
{
    const int u = blockIdx.x, b = blockIdx.z;
    int ti = (int)((sqrtf(8.0f * (float)u + 1.0f) - 1.0f) * 0.5f);
    while ((ti + 1) * (ti + 2) / 2 <= u) ++ti;
    while (ti * (ti + 1) / 2 > u) --ti;
    const int tj = u - ti * (ti + 1) / 2;
    const bf16_t* A  = PrQ + (long)b * S_LEN * D_DIM;
    const bf16_t* Bt = PrK + (long)b * S_LEN * D_DIM;
    bf16_t* C        = SC  + (long)b * S_LEN * S_LEN;
    const int m0 = ti * BM, n0 = tj * BN;
    f32x4 acc[4][4];
    gemm_bt_core(A, Bt, D_DIM, D_DIM, m0, n0, D_DIM / BK, acc);
    const int lane = threadIdx.x & 63, w = threadIdx.x >> 6;
    const int wr = w >> 1, wc = w & 1;
    const int r0 = m0 + wr * 64 + (lane >> 4) * 4;
    const int c0 = n0 + wc * 64 + (lane & 15);
#pragma unroll
    for (int mt = 0; mt < 4; ++mt)
#pragma unroll
        for (int nt = 0; nt < 4; ++nt) {
            const int col = c0 + nt * 16;
#pragma unroll
            for (int r = 0; r < 4; ++r) {
                const int row = r0 + mt * 16 + r;
                C[(long)row * S_LEN + col] = (bf16_t)(acc[mt][nt][r] * 0.03125f);
            }
        }
}

// causal softmax, wave-per-row, register-resident, shuffle reductions.
__global__ __launch_bounds__(256) void k_softmax(bf16_t* __restrict__ SC)
{
    const int w = threadIdx.x >> 6, lane = threadIdx.x & 63;
    const int i = blockIdx.x * 4 + w;
    const int b = blockIdx.y;
    bf16_t* row = SC + ((long)b * S_LEN + i) * S_LEN;
    const int n    = i + 1;
    const int jend = ((i >> 7) + 1) << 7;
    const int nch  = (jend + 511) >> 9;     // 512-elem chunks to touch (1..4)
    float x[4][8];
    float mx = -1e30f;
#pragma unroll
    for (int c = 0; c < 4; ++c) {
        if (c < nch) {
            bf16x8 vv = *(const bf16x8*)(row + c * 512 + lane * 8);
#pragma unroll
            for (int e = 0; e < 8; ++e) {
                const int j = c * 512 + lane * 8 + e;
                const float f = (j < n) ? (float)vv[e] : -1e30f;
                x[c][e] = f;
                mx = fmaxf(mx, f);
            }
        }
    }
#pragma unroll
    for (int d = 1; d < 64; d <<= 1) mx = fmaxf(mx, __shfl_xor(mx, d, 64));
    float sm = 0.f;
#pragma unroll
    for (int c = 0; c < 4; ++c) {
        if (c < nch) {
#pragma unroll
            for (int e = 0; e < 8; ++e) {
                const int j = c * 512 + lane * 8 + e;
                float p = (j < n) ? __expf(x[c][e] - mx) : 0.f;
                x[c][e] = p;
                sm += p;
            }
        }
    }
#pragma unroll
    for (int d = 1; d < 64; d <<= 1) sm += __shfl_xor(sm, d, 64);
    const float inv = 1.0f / sm;
#pragma unroll
    for (int c = 0; c < 4; ++c) {
        if (c < nch) {
            bf16x8 o;
#pragma unroll
            for (int e = 0; e < 8; ++e) o[e] = (bf16_t)(x[c][e] * inv);
            *(bf16x8*)(row + c * 512 + lane * 8) = o;
        }
    }
}

// out = P @ WVt^T, fp32 out; K-loop truncated at diagonal tile. Heavy-first.
__global__ __launch_bounds__(256) void k_gemm_pv(
    const bf16_t* __restrict__ SC, const bf16_t* __restrict__ WVt,
    float* __restrict__ Out)
{
    const int ti = (S_LEN / BM - 1) - blockIdx.y, b = blockIdx.z;
    const bf16_t* A  = SC  + (long)b * S_LEN * S_LEN;
    const bf16_t* Bt = WVt + (long)b * D_DIM * S_LEN;
    float* C         = Out + (long)b * S_LEN * D_DIM;
    const int m0 = ti * BM, n0 = blockIdx.x * BN;
    f32x4 acc[4][4];
    gemm_bt_core(A, Bt, S_LEN, S_LEN, m0, n0, (ti + 1) * (BM / BK), acc);
    const int lane = threadIdx.x & 63, w = threadIdx.x >> 6;
    const int wr = w >> 1, wc = w & 1;
    const int r0 = m0 + wr * 64 + (lane >> 4) * 4;
    const int c0 = n0 + wc * 64 + (lane & 15);
#pragma unroll
    for (int mt = 0; mt < 4; ++mt)
#pragma unroll
        for (int nt = 0; nt < 4; ++nt) {
            const int col = c0 + nt * 16;
#pragma unroll
            for (int r = 0; r < 4; ++r) {
                const int row = r0 + mt * 16 + r;
                C[(long)row * D_DIM + col] = acc[mt][nt][r];
            }
        }
}

extern "C" void kernel_launch(void* const* d_in, const int* in_sizes, int n_in,
                              void* d_out, int out_size, void* d_ws, size_t ws_size,
                              hipStream_t stream)
{
    (void)in_sizes; (void)n_in; (void)out_size; (void)ws_size;
    const float* q  = (const float*)d_in[0];
    const float* k  = (const float*)d_in[1];
    const float* v  = (const float*)d_in[2];
    // d_in[3] = mask: causal triu(1) — applied analytically
    const float* Wq = (const float*)d_in[4];
    const float* bq = (const float*)d_in[5];
    const float* Wk = (const float*)d_in[6];
    const float* bk = (const float*)d_in[7];
    const float* Wv = (const float*)d_in[8];
    const float* bv = (const float*)d_in[9];
    float* out = (float*)d_out;

    // ws layout (bf16 elems): Wt[3*D*D] | Xb[3*B*S*D] (reused as SC[B*S*S]) | Pr[3*B*S*D] | WVt[B*D*S]
    bf16_t* ws = (bf16_t*)d_ws;
    const long nW = (long)D_DIM * D_DIM;           // 1,048,576
    const long nX = (long)NB * S_LEN * D_DIM;      // 8,388,608
    bf16_t* Wt  = ws;
    bf16_t* Xb  = Wt + 3 * nW;
    bf16_t* SC  = Xb;              // aliases Xb: Xb dead after projections
    bf16_t* Pr  = Xb + 3 * nX;
    bf16_t* WVt = Pr + 3 * nX;
    bf16_t* PrQ = Pr;
    bf16_t* PrK = Pr + nX;
    bf16_t* PrV = Pr + 2 * nX;

    k_f2b        <<<dim3(8192, 1, 3),   256,        0, stream>>>(q, k, v, Xb);
    k_tw         <<<dim3(16, 16, 3),    256,        0, stream>>>(Wq, Wk, Wv, Wt);
    k_gemm_proj  <<<dim3(64, 8, 3),     256,        0, stream>>>(Xb, Wt, bq, bk, bv, Pr);
    k_tv         <<<dim3(16, 32, NB),   256,        0, stream>>>(PrV, WVt);
    k_gemm_scores<<<dim3(136, 1, NB),   256,        0, stream>>>(PrQ, PrK, SC);
    k_softmax    <<<dim3(S_LEN / 4, NB),256,        0, stream>>>(SC);
    k_gemm_pv    <<<dim3(8, 16, NB),    256,        0, stream>>>(SC, WVt, out);
}